// Round 1
// baseline (1935.820 us; speedup 1.0000x reference)
//
#include <hip/hip_runtime.h>
#include <math.h>

#define BQ 4
#define SQ 2048
#define DQ 512
#define YQ 8922
#define TQ 32
#define EQ 100
#define EP 128      // E padded for MFMA K-steps
#define KQ 9
#define LDK 136     // LDS leading dim (bf16 elems): 272B rows -> ~2-way banks
#define YPAD 8960   // U rows padded to multiple of 128

typedef float f32x4 __attribute__((ext_vector_type(4)));
typedef short s16x8 __attribute__((ext_vector_type(8)));

static __device__ __forceinline__ f32x4 mfma16(s16x8 a, s16x8 b, f32x4 c) {
  return __builtin_amdgcn_mfma_f32_16x16x32_bf16(a, b, c, 0, 0, 0);
}

static __device__ __forceinline__ ushort f2bf(float f) {
  union { float f; unsigned u; } v; v.f = f;
  unsigned r = (v.u + 0x7FFFu + ((v.u >> 16) & 1u)) >> 16;
  return (ushort)r;
}

// unaligned (4B) 16-byte load
static __device__ __forceinline__ f32x4 ld4u(const float* p) {
  f32x4 v; __builtin_memcpy(&v, p, 16); return v;
}

// ---------------- prep: x -> bf16 [B][S][D] and transposed bf16 [B][D][S] ----
__global__ void k_prep_x(const float* __restrict__ x, ushort* __restrict__ xb,
                         ushort* __restrict__ xT) {
  __shared__ ushort sm[32][33];
  int b = blockIdx.z;
  int s0 = blockIdx.x * 32;
  int d0 = blockIdx.y * 32;
  int tx = threadIdx.x, ty = threadIdx.y;
  float v = x[((size_t)b * SQ + s0 + ty) * DQ + d0 + tx];
  ushort h = f2bf(v);
  xb[((size_t)b * SQ + s0 + ty) * DQ + d0 + tx] = h;
  sm[ty][tx] = h;
  __syncthreads();
  xT[((size_t)b * DQ + d0 + ty) * SQ + s0 + tx] = sm[tx][ty];
}

// ---------------- pack conv_w [D][E][K] -> Wp bf16 [K][D][EP] (e>=100 -> 0) --
__global__ void k_pack_w(const float* __restrict__ cw, ushort* __restrict__ Wp) {
  int i = blockIdx.x * 256 + threadIdx.x;
  if (i >= KQ * DQ * EP) return;
  int e = i & (EP - 1);
  int d = (i >> 7) & (DQ - 1);
  int kk = i >> 16;
  float v = (e < EQ) ? cw[((size_t)d * EQ + e) * KQ + kk] : 0.f;
  Wp[i] = f2bf(v);
}

// ---------------- conv + maxpool + tanh + scale -> U bf16 [YPAD][D] ---------
__launch_bounds__(256, 2)
__global__ void k_conv(const int* __restrict__ c2t, const float* __restrict__ embed,
                       const ushort* __restrict__ Wp, const float* __restrict__ cb,
                       ushort* __restrict__ U) {
  __shared__ union {
    struct { ushort A[4 * TQ * LDK]; ushort B[128 * LDK]; } s;  // 34816 B each
    float red[128 * 132];                                       // 67584 B
  } sm;
  const f32x4 fz4 = {0.f, 0.f, 0.f, 0.f};
  const s16x8 sz8 = {0, 0, 0, 0, 0, 0, 0, 0};
  int tid = threadIdx.x;
  int d0 = blockIdx.x * 128;
  int y0 = blockIdx.y * 4;

  // stage all title embeddings for 4 labels: [4][32][LDK] bf16, e-padded
  {
    int row = tid >> 1;
    int half = tid & 1;
    int yl = row >> 5, t = row & 31;
    int y = y0 + yl;
    ushort* dst = &sm.s.A[(yl * TQ + t) * LDK + half * 64];
    const float* src = 0;
    if (y < YQ) src = embed + (size_t)c2t[y * TQ + t] * EQ + half * 64;
    #pragma unroll
    for (int j = 0; j < 16; ++j) {
      int e = half * 64 + j * 4;
      f32x4 v = fz4;
      if (src != 0 && e + 4 <= EQ) v = *(const f32x4*)(src + j * 4);
      ushort4 h = make_ushort4(f2bf(v.x), f2bf(v.y), f2bf(v.z), f2bf(v.w));
      *(ushort4*)(dst + j * 4) = h;
    }
  }

  f32x4 acc[4][4];
  #pragma unroll
  for (int i = 0; i < 4; ++i)
    #pragma unroll
    for (int j = 0; j < 4; ++j) acc[i][j] = fz4;

  int lane = tid & 63, wave = tid >> 6;
  int wm = wave & 1, wn = wave >> 1;
  int lr = lane & 15, lk = (lane >> 4) * 8;

  for (int kk = 0; kk < KQ; ++kk) {
    __syncthreads();
    const ushort* src = Wp + ((size_t)kk * DQ + d0) * EP;
    #pragma unroll
    for (int it = 0; it < 8; ++it) {
      int gi = tid + it * 256;
      int r = gi >> 4, g = (gi & 15) * 8;
      *(s16x8*)&sm.s.B[r * LDK + g] = *(const s16x8*)(src + (size_t)r * EP + g);
    }
    __syncthreads();
    #pragma unroll
    for (int ee = 0; ee < 4; ++ee) {
      s16x8 af[4], bfr[4];
      #pragma unroll
      for (int i = 0; i < 4; ++i) {
        int rowm = wm * 64 + i * 16 + lr;
        int yl = rowm >> 5;
        int ts = (rowm & 31) + kk - 4;   // shifted time index
        s16x8 a = sz8;
        if ((unsigned)ts < (unsigned)TQ)
          a = *(const s16x8*)&sm.s.A[(yl * TQ + ts) * LDK + ee * 32 + lk];
        af[i] = a;
      }
      #pragma unroll
      for (int i = 0; i < 4; ++i)
        bfr[i] = *(const s16x8*)&sm.s.B[(wn * 64 + i * 16 + lr) * LDK + ee * 32 + lk];
      #pragma unroll
      for (int i = 0; i < 4; ++i)
        #pragma unroll
        for (int j = 0; j < 4; ++j)
          acc[i][j] = mfma16(af[i], bfr[j], acc[i][j]);
    }
  }

  // epilogue: dump 128x128 f32 tile, max over t (32 rows / label), tanh, scale
  __syncthreads();
  {
    int rb = wm * 64 + (lane >> 4) * 4;
    int cb_ = wn * 64 + lr;
    #pragma unroll
    for (int i = 0; i < 4; ++i)
      #pragma unroll
      for (int j = 0; j < 4; ++j)
        #pragma unroll
        for (int q = 0; q < 4; ++q)
          sm.red[(rb + i * 16 + q) * 132 + cb_ + j * 16] = acc[i][j][q];
  }
  __syncthreads();
  #pragma unroll
  for (int rep = 0; rep < 2; ++rep) {
    int idx = tid + rep * 256;
    int yl = idx >> 7, d = idx & 127;
    float mx = -3.0e38f;
    #pragma unroll 8
    for (int t = 0; t < TQ; ++t)
      mx = fmaxf(mx, sm.red[(yl * TQ + t) * 132 + d]);
    int y = y0 + yl;
    if (y < YQ) {
      // fold 1/sqrt(D) attention scale into U
      float u = tanhf(mx + cb[d0 + d]) * 0.04419417382415922f;
      U[(size_t)y * DQ + d0 + d] = f2bf(u);
    }
  }
}

// ---------------- scores = U . xb^T -> raw scores into d_out alpha slot -----
__launch_bounds__(256, 2)
__global__ void k_scores(const ushort* __restrict__ U, const ushort* __restrict__ xb,
                         float* __restrict__ sc) {
  __shared__ ushort sA[128 * LDK];
  __shared__ ushort sB[128 * LDK];
  const f32x4 fz4 = {0.f, 0.f, 0.f, 0.f};
  int tid = threadIdx.x;
  int s0 = blockIdx.x * 128;
  int y0 = blockIdx.y * 128;
  int b = blockIdx.z;
  const ushort* Ap = U + (size_t)y0 * DQ;
  const ushort* Bp = xb + ((size_t)b * SQ + s0) * DQ;
  f32x4 acc[4][4];
  #pragma unroll
  for (int i = 0; i < 4; ++i)
    #pragma unroll
    for (int j = 0; j < 4; ++j) acc[i][j] = fz4;
  int lane = tid & 63, wave = tid >> 6;
  int wm = wave & 1, wn = wave >> 1;
  int lr = lane & 15, lk = (lane >> 4) * 8;

  for (int kc = 0; kc < DQ; kc += 128) {
    __syncthreads();
    #pragma unroll
    for (int it = 0; it < 8; ++it) {
      int gi = tid + it * 256;
      int r = gi >> 4, g = (gi & 15) * 8;
      *(s16x8*)&sA[r * LDK + g] = *(const s16x8*)(Ap + (size_t)r * DQ + kc + g);
      *(s16x8*)&sB[r * LDK + g] = *(const s16x8*)(Bp + (size_t)r * DQ + kc + g);
    }
    __syncthreads();
    #pragma unroll
    for (int ks = 0; ks < 4; ++ks) {
      s16x8 af[4], bfr[4];
      #pragma unroll
      for (int i = 0; i < 4; ++i)
        af[i] = *(const s16x8*)&sA[(wm * 64 + i * 16 + lr) * LDK + ks * 32 + lk];
      #pragma unroll
      for (int i = 0; i < 4; ++i)
        bfr[i] = *(const s16x8*)&sB[(wn * 64 + i * 16 + lr) * LDK + ks * 32 + lk];
      #pragma unroll
      for (int i = 0; i < 4; ++i)
        #pragma unroll
        for (int j = 0; j < 4; ++j)
          acc[i][j] = mfma16(af[i], bfr[j], acc[i][j]);
    }
  }
  float* out = sc + (size_t)b * YQ * SQ;
  int rb = wm * 64 + (lane >> 4) * 4;
  int cb_ = wn * 64 + lr;
  #pragma unroll
  for (int i = 0; i < 4; ++i)
    #pragma unroll
    for (int j = 0; j < 4; ++j) {
      int col = s0 + cb_ + j * 16;
      #pragma unroll
      for (int q = 0; q < 4; ++q) {
        int r = y0 + rb + i * 16 + q;
        if (r < YQ) out[(size_t)r * SQ + col] = acc[i][j][q];
      }
    }
}

// ---------------- in-place softmax over S (one block per (b,y) row) ---------
__global__ void k_softmax(float* __restrict__ a) {
  float* p = a + (size_t)blockIdx.x * SQ;
  int tid = threadIdx.x;
  int lane = tid & 63, wave = tid >> 6;
  float v[8];
  #pragma unroll
  for (int i = 0; i < 8; ++i) v[i] = p[tid + i * 256];
  float mx = v[0];
  #pragma unroll
  for (int i = 1; i < 8; ++i) mx = fmaxf(mx, v[i]);
  #pragma unroll
  for (int o = 32; o > 0; o >>= 1) mx = fmaxf(mx, __shfl_xor(mx, o));
  __shared__ float red[8];
  if (lane == 0) red[wave] = mx;
  __syncthreads();
  mx = fmaxf(fmaxf(red[0], red[1]), fmaxf(red[2], red[3]));
  float s = 0.f;
  #pragma unroll
  for (int i = 0; i < 8; ++i) { v[i] = __expf(v[i] - mx); s += v[i]; }
  #pragma unroll
  for (int o = 32; o > 0; o >>= 1) s += __shfl_xor(s, o);
  if (lane == 0) red[4 + wave] = s;
  __syncthreads();
  s = (red[4] + red[5]) + (red[6] + red[7]);
  float inv = 1.0f / s;
  #pragma unroll
  for (int i = 0; i < 8; ++i) p[tid + i * 256] = v[i] * inv;
}

// ---------------- m = alpha . x  (B-op = pre-transposed xT) -----------------
__launch_bounds__(256, 2)
__global__ void k_pv(const float* __restrict__ alpha, const ushort* __restrict__ xT,
                     float* __restrict__ mo) {
  __shared__ ushort sA[128 * LDK];
  __shared__ ushort sB[128 * LDK];
  const f32x4 fz4 = {0.f, 0.f, 0.f, 0.f};
  int tid = threadIdx.x;
  int d0 = blockIdx.x * 128;
  int y0 = blockIdx.y * 128;
  int b = blockIdx.z;
  const float* Ap = alpha + ((size_t)b * YQ + y0) * SQ;
  const ushort* Bp = xT + ((size_t)b * DQ + d0) * SQ;
  f32x4 acc[4][4];
  #pragma unroll
  for (int i = 0; i < 4; ++i)
    #pragma unroll
    for (int j = 0; j < 4; ++j) acc[i][j] = fz4;
  int lane = tid & 63, wave = tid >> 6;
  int wm = wave & 1, wn = wave >> 1;
  int lr = lane & 15, lk = (lane >> 4) * 8;

  for (int kc = 0; kc < SQ; kc += 128) {
    __syncthreads();
    #pragma unroll
    for (int it = 0; it < 8; ++it) {
      int gi = tid + it * 256;
      int r = gi >> 4, g = (gi & 15) * 8;
      int y = y0 + r;
      ushort4 h0 = make_ushort4(0, 0, 0, 0), h1 = make_ushort4(0, 0, 0, 0);
      if (y < YQ) {
        f32x4 v0 = ld4u(Ap + (size_t)r * SQ + kc + g);
        f32x4 v1 = ld4u(Ap + (size_t)r * SQ + kc + g + 4);
        h0 = make_ushort4(f2bf(v0.x), f2bf(v0.y), f2bf(v0.z), f2bf(v0.w));
        h1 = make_ushort4(f2bf(v1.x), f2bf(v1.y), f2bf(v1.z), f2bf(v1.w));
      }
      *(ushort4*)&sA[r * LDK + g] = h0;
      *(ushort4*)&sA[r * LDK + g + 4] = h1;
      *(s16x8*)&sB[r * LDK + g] = *(const s16x8*)(Bp + (size_t)r * SQ + kc + g);
    }
    __syncthreads();
    #pragma unroll
    for (int ks = 0; ks < 4; ++ks) {
      s16x8 af[4], bfr[4];
      #pragma unroll
      for (int i = 0; i < 4; ++i)
        af[i] = *(const s16x8*)&sA[(wm * 64 + i * 16 + lr) * LDK + ks * 32 + lk];
      #pragma unroll
      for (int i = 0; i < 4; ++i)
        bfr[i] = *(const s16x8*)&sB[(wn * 64 + i * 16 + lr) * LDK + ks * 32 + lk];
      #pragma unroll
      for (int i = 0; i < 4; ++i)
        #pragma unroll
        for (int j = 0; j < 4; ++j)
          acc[i][j] = mfma16(af[i], bfr[j], acc[i][j]);
    }
  }
  float* out = mo + (size_t)b * YQ * DQ;
  int rb = wm * 64 + (lane >> 4) * 4;
  int cb_ = wn * 64 + lr;
  #pragma unroll
  for (int i = 0; i < 4; ++i)
    #pragma unroll
    for (int j = 0; j < 4; ++j) {
      int col = d0 + cb_ + j * 16;
      #pragma unroll
      for (int q = 0; q < 4; ++q) {
        int r = y0 + rb + i * 16 + q;
        if (r < YQ) out[(size_t)r * DQ + col] = acc[i][j][q];
      }
    }
}

// ---------------- y = m . final_w + b ; BCE loss accumulate -----------------
__global__ void k_final(const float* __restrict__ m_in, const float* __restrict__ fw,
                        const float* __restrict__ fb, const float* __restrict__ tgt,
                        float* __restrict__ yo, float* __restrict__ lacc) {
  int y = blockIdx.x;
  int lane = threadIdx.x & 63;
  int b = threadIdx.x >> 6;      // 4 waves = 4 batches
  const float* mp = m_in + ((size_t)b * YQ + y) * DQ;
  const float* wp = fw + (size_t)y * DQ;
  float s = 0.f;
  #pragma unroll
  for (int i = 0; i < 8; ++i) {
    int e = lane + i * 64;
    s += mp[e] * wp[e];
  }
  #pragma unroll
  for (int o = 32; o > 0; o >>= 1) s += __shfl_xor(s, o);
  if (lane == 0) {
    float yv = s + fb[y];
    yo[(size_t)b * YQ + y] = yv;
    float t = tgt[(size_t)b * YQ + y];
    float l = fmaxf(yv, 0.f) - yv * t + log1pf(__expf(-fabsf(yv)));
    atomicAdd(lacc, l);
  }
}

__global__ void k_loss_fin(const float* __restrict__ lacc, float* __restrict__ out) {
  out[0] = lacc[0] * (1.0f / (float)(BQ * YQ));
}

extern "C" void kernel_launch(void* const* d_in, const int* in_sizes, int n_in,
                              void* d_out, int out_size, void* d_ws, size_t ws_size,
                              hipStream_t stream) {
  const float* x      = (const float*)d_in[0];
  const float* target = (const float*)d_in[1];
  const int*   c2t    = (const int*)d_in[2];
  const float* embed  = (const float*)d_in[3];
  const float* cw     = (const float*)d_in[4];
  const float* cb     = (const float*)d_in[5];
  const float* fw     = (const float*)d_in[6];
  const float* fb     = (const float*)d_in[7];

  char* ws = (char*)d_ws;
  ushort* xb = (ushort*)(ws);                   //  8,388,608 B
  ushort* xT = (ushort*)(ws + 8388608);         //  8,388,608 B
  ushort* Wp = (ushort*)(ws + 16777216);        //  1,179,648 B
  ushort* U  = (ushort*)(ws + 17956864);        //  9,175,040 B (YPAD x D bf16)
  float* lacc = (float*)(ws + 27131904);        //  4 B

  float* out       = (float*)d_out;
  float* out_y     = out;                               // [B][Y]
  float* out_loss  = out + (size_t)BQ * YQ;             // scalar
  float* out_alpha = out + (size_t)BQ * YQ + 1;         // [B][Y][S]
  float* out_m     = out_alpha + (size_t)BQ * YQ * SQ;  // [B][Y][D]

  hipMemsetAsync(U, 0, (size_t)YPAD * DQ * 2, stream);
  hipMemsetAsync(lacc, 0, 4, stream);

  k_prep_x<<<dim3(SQ / 32, DQ / 32, BQ), dim3(32, 32), 0, stream>>>(x, xb, xT);
  k_pack_w<<<dim3((KQ * DQ * EP + 255) / 256), 256, 0, stream>>>(cw, Wp);
  k_conv<<<dim3(4, (YQ + 3) / 4), 256, 0, stream>>>(c2t, embed, Wp, cb, U);
  k_scores<<<dim3(SQ / 128, (YQ + 127) / 128, BQ), 256, 0, stream>>>(U, xb, out_alpha);
  k_softmax<<<dim3(BQ * YQ), 256, 0, stream>>>(out_alpha);
  k_pv<<<dim3(DQ / 128, (YQ + 127) / 128, BQ), 256, 0, stream>>>(out_alpha, xT, out_m);
  k_final<<<dim3(YQ), 256, 0, stream>>>(out_m, fw, fb, target, out_y, lacc);
  k_loss_fin<<<1, 1, 0, stream>>>(lacc, out_loss);
}

// Round 2
// 1880.255 us; speedup vs baseline: 1.0296x; 1.0296x over previous
//
#include <hip/hip_runtime.h>
#include <math.h>

#define BQ 4
#define SQ 2048
#define DQ 512
#define YQ 8922
#define TQ 32
#define EQ 100
#define EP 128      // E padded for MFMA K-steps
#define KQ 9
#define LD 128      // LDS leading dim (bf16 elems) = 256B rows, XOR-swizzled
#define YPAD 8960   // U rows padded to multiple of 128

typedef float f32x4 __attribute__((ext_vector_type(4)));
typedef short s16x8 __attribute__((ext_vector_type(8)));

static __device__ __forceinline__ f32x4 mfma16(s16x8 a, s16x8 b, f32x4 c) {
  return __builtin_amdgcn_mfma_f32_16x16x32_bf16(a, b, c, 0, 0, 0);
}

static __device__ __forceinline__ ushort f2bf(float f) {
  union { float f; unsigned u; } v; v.f = f;
  unsigned r = (v.u + 0x7FFFu + ((v.u >> 16) & 1u)) >> 16;
  return (ushort)r;
}

// unaligned (4B) 16-byte load
static __device__ __forceinline__ f32x4 ld4u(const float* p) {
  f32x4 v; __builtin_memcpy(&v, p, 16); return v;
}

// T2 swizzle: 16B-chunk index XOR'd with row&7 (bijective within 8-chunk half)
static __device__ __forceinline__ int swz_chunk(int row, int chunk) {
  return chunk ^ (row & 7);
}

// ---------------- prep: x -> bf16 [B][S][D] and transposed bf16 [B][D][S] ----
__global__ void k_prep_x(const float* __restrict__ x, ushort* __restrict__ xb,
                         ushort* __restrict__ xT) {
  __shared__ ushort sm[32][33];
  int b = blockIdx.z;
  int s0 = blockIdx.x * 32;
  int d0 = blockIdx.y * 32;
  int tx = threadIdx.x, ty = threadIdx.y;
  float v = x[((size_t)b * SQ + s0 + ty) * DQ + d0 + tx];
  ushort h = f2bf(v);
  xb[((size_t)b * SQ + s0 + ty) * DQ + d0 + tx] = h;
  sm[ty][tx] = h;
  __syncthreads();
  xT[((size_t)b * DQ + d0 + ty) * SQ + s0 + tx] = sm[tx][ty];
}

// ---------------- pack conv_w [D][E][K] -> Wp bf16 [K][D][EP] (e>=100 -> 0) --
__global__ void k_pack_w(const float* __restrict__ cw, ushort* __restrict__ Wp) {
  int i = blockIdx.x * 256 + threadIdx.x;
  if (i >= KQ * DQ * EP) return;
  int e = i & (EP - 1);
  int d = (i >> 7) & (DQ - 1);
  int kk = i >> 16;
  float v = (e < EQ) ? cw[((size_t)d * EQ + e) * KQ + kk] : 0.f;
  Wp[i] = f2bf(v);
}

// ---------------- conv + maxpool + tanh + scale -> U bf16 [YPAD][D] ---------
__launch_bounds__(256, 2)
__global__ void k_conv(const int* __restrict__ c2t, const float* __restrict__ embed,
                       const ushort* __restrict__ Wp, const float* __restrict__ cb,
                       ushort* __restrict__ U) {
  __shared__ union {
    struct { ushort A[4 * TQ * LD]; ushort B[128 * LD]; } s;   // 32768 B each
    float red[128 * 132];                                      // 67584 B
  } sm;
  const f32x4 fz4 = {0.f, 0.f, 0.f, 0.f};
  const s16x8 sz8 = {0, 0, 0, 0, 0, 0, 0, 0};
  int tid = threadIdx.x;
  int d0 = blockIdx.x * 128;
  int y0 = blockIdx.y * 4;

  // stage all title embeddings for 4 labels: [4][32] rows x [LD] bf16, swizzled
  {
    int row = tid >> 1;
    int half = tid & 1;
    int yl = row >> 5, t = row & 31;
    int y = y0 + yl;
    const float* src = 0;
    if (y < YQ) src = embed + (size_t)c2t[y * TQ + t] * EQ + half * 64;
    #pragma unroll
    for (int j = 0; j < 16; ++j) {
      int e = half * 64 + j * 4;
      f32x4 v = fz4;
      if (src != 0 && e + 4 <= EQ) v = *(const f32x4*)(src + j * 4);
      ushort4 h = make_ushort4(f2bf(v.x), f2bf(v.y), f2bf(v.z), f2bf(v.w));
      int col = half * 64 + j * 4;
      int pc = swz_chunk(row, col >> 3);
      *(ushort4*)&sm.s.A[row * LD + pc * 8 + (col & 7)] = h;
    }
  }

  f32x4 acc[4][4];
  #pragma unroll
  for (int i = 0; i < 4; ++i)
    #pragma unroll
    for (int j = 0; j < 4; ++j) acc[i][j] = fz4;

  int lane = tid & 63, wave = tid >> 6;
  int wm = wave & 1, wn = wave >> 1;
  int lr = lane & 15, lg = lane >> 4;

  for (int kk = 0; kk < KQ; ++kk) {
    __syncthreads();
    const ushort* src = Wp + ((size_t)kk * DQ + d0) * EP;
    #pragma unroll
    for (int it = 0; it < 8; ++it) {
      int gi = tid + it * 256;
      int r = gi >> 4, g = gi & 15;
      *(s16x8*)&sm.s.B[r * LD + swz_chunk(r, g) * 8] =
          *(const s16x8*)(src + (size_t)r * EP + g * 8);
    }
    __syncthreads();
    #pragma unroll
    for (int ee = 0; ee < 4; ++ee) {
      s16x8 af[4], bfr[4];
      #pragma unroll
      for (int i = 0; i < 4; ++i) {
        int rowm = wm * 64 + i * 16 + lr;
        int yl = rowm >> 5;
        int ts = (rowm & 31) + kk - 4;   // shifted time index
        s16x8 a = sz8;
        if ((unsigned)ts < (unsigned)TQ) {
          int row = yl * TQ + ts;
          a = *(const s16x8*)&sm.s.A[row * LD + swz_chunk(row, ee * 4 + lg) * 8];
        }
        af[i] = a;
      }
      #pragma unroll
      for (int i = 0; i < 4; ++i) {
        int row = wn * 64 + i * 16 + lr;
        bfr[i] = *(const s16x8*)&sm.s.B[row * LD + swz_chunk(row, ee * 4 + lg) * 8];
      }
      #pragma unroll
      for (int i = 0; i < 4; ++i)
        #pragma unroll
        for (int j = 0; j < 4; ++j)
          acc[i][j] = mfma16(af[i], bfr[j], acc[i][j]);
    }
  }

  // epilogue: dump 128x128 f32 tile, max over t (32 rows / label), tanh, scale
  __syncthreads();
  {
    int rb = wm * 64 + lg * 4;
    int cb_ = wn * 64 + lr;
    #pragma unroll
    for (int i = 0; i < 4; ++i)
      #pragma unroll
      for (int j = 0; j < 4; ++j)
        #pragma unroll
        for (int q = 0; q < 4; ++q)
          sm.red[(rb + i * 16 + q) * 132 + cb_ + j * 16] = acc[i][j][q];
  }
  __syncthreads();
  #pragma unroll
  for (int rep = 0; rep < 2; ++rep) {
    int idx = tid + rep * 256;
    int yl = idx >> 7, d = idx & 127;
    float mx = -3.0e38f;
    #pragma unroll 8
    for (int t = 0; t < TQ; ++t)
      mx = fmaxf(mx, sm.red[(yl * TQ + t) * 132 + d]);
    int y = y0 + yl;
    if (y < YQ) {
      // fold 1/sqrt(D) attention scale into U
      float u = tanhf(mx + cb[d0 + d]) * 0.04419417382415922f;
      U[(size_t)y * DQ + d0 + d] = f2bf(u);
    }
  }
}

// ---------------- scores = U . xb^T -> raw scores into d_out alpha slot -----
__launch_bounds__(256, 2)
__global__ void k_scores(const ushort* __restrict__ U, const ushort* __restrict__ xb,
                         float* __restrict__ sc) {
  __shared__ ushort sA[128 * LD];
  __shared__ ushort sB[128 * LD];
  const f32x4 fz4 = {0.f, 0.f, 0.f, 0.f};
  int tid = threadIdx.x;
  int s0 = blockIdx.x * 128;
  int y0 = blockIdx.y * 128;
  int b = blockIdx.z;
  const ushort* Ap = U + (size_t)y0 * DQ;
  const ushort* Bp = xb + ((size_t)b * SQ + s0) * DQ;
  f32x4 acc[4][4];
  #pragma unroll
  for (int i = 0; i < 4; ++i)
    #pragma unroll
    for (int j = 0; j < 4; ++j) acc[i][j] = fz4;
  int lane = tid & 63, wave = tid >> 6;
  int wm = wave & 1, wn = wave >> 1;
  int lr = lane & 15, lg = lane >> 4;

  for (int kc = 0; kc < DQ; kc += 128) {
    __syncthreads();
    #pragma unroll
    for (int it = 0; it < 8; ++it) {
      int gi = tid + it * 256;
      int r = gi >> 4, g = gi & 15;
      int pofs = r * LD + swz_chunk(r, g) * 8;
      *(s16x8*)&sA[pofs] = *(const s16x8*)(Ap + (size_t)r * DQ + kc + g * 8);
      *(s16x8*)&sB[pofs] = *(const s16x8*)(Bp + (size_t)r * DQ + kc + g * 8);
    }
    __syncthreads();
    #pragma unroll
    for (int ks = 0; ks < 4; ++ks) {
      s16x8 af[4], bfr[4];
      #pragma unroll
      for (int i = 0; i < 4; ++i) {
        int row = wm * 64 + i * 16 + lr;
        af[i] = *(const s16x8*)&sA[row * LD + swz_chunk(row, ks * 4 + lg) * 8];
      }
      #pragma unroll
      for (int i = 0; i < 4; ++i) {
        int row = wn * 64 + i * 16 + lr;
        bfr[i] = *(const s16x8*)&sB[row * LD + swz_chunk(row, ks * 4 + lg) * 8];
      }
      #pragma unroll
      for (int i = 0; i < 4; ++i)
        #pragma unroll
        for (int j = 0; j < 4; ++j)
          acc[i][j] = mfma16(af[i], bfr[j], acc[i][j]);
    }
  }
  float* out = sc + (size_t)b * YQ * SQ;
  int rb = wm * 64 + lg * 4;
  int cb_ = wn * 64 + lr;
  #pragma unroll
  for (int i = 0; i < 4; ++i)
    #pragma unroll
    for (int j = 0; j < 4; ++j) {
      int col = s0 + cb_ + j * 16;
      #pragma unroll
      for (int q = 0; q < 4; ++q) {
        int r = y0 + rb + i * 16 + q;
        if (r < YQ) out[(size_t)r * SQ + col] = acc[i][j][q];
      }
    }
}

// ---- in-place softmax over S (one block per (b,y) row); optional bf16 copy --
__global__ void k_softmax(float* __restrict__ a, ushort* __restrict__ abf) {
  float* p = a + (size_t)blockIdx.x * SQ;
  int tid = threadIdx.x;
  int lane = tid & 63, wave = tid >> 6;
  float v[8];
  #pragma unroll
  for (int i = 0; i < 8; ++i) v[i] = p[tid + i * 256];
  float mx = v[0];
  #pragma unroll
  for (int i = 1; i < 8; ++i) mx = fmaxf(mx, v[i]);
  #pragma unroll
  for (int o = 32; o > 0; o >>= 1) mx = fmaxf(mx, __shfl_xor(mx, o));
  __shared__ float red[8];
  if (lane == 0) red[wave] = mx;
  __syncthreads();
  mx = fmaxf(fmaxf(red[0], red[1]), fmaxf(red[2], red[3]));
  float s = 0.f;
  #pragma unroll
  for (int i = 0; i < 8; ++i) { v[i] = __expf(v[i] - mx); s += v[i]; }
  #pragma unroll
  for (int o = 32; o > 0; o >>= 1) s += __shfl_xor(s, o);
  if (lane == 0) red[4 + wave] = s;
  __syncthreads();
  s = (red[4] + red[5]) + (red[6] + red[7]);
  float inv = 1.0f / s;
  ushort* q = abf ? abf + (size_t)blockIdx.x * SQ : 0;
  #pragma unroll
  for (int i = 0; i < 8; ++i) {
    float av = v[i] * inv;
    p[tid + i * 256] = av;
    if (q) q[tid + i * 256] = f2bf(av);
  }
}

// ---------------- m = alpha . x  (B-op = pre-transposed xT) -----------------
template <bool BF16A>
__launch_bounds__(256, 2)
__global__ void k_pv(const float* __restrict__ alpha, const ushort* __restrict__ abf,
                     const ushort* __restrict__ xT, float* __restrict__ mo) {
  __shared__ ushort sA[128 * LD];
  __shared__ ushort sB[128 * LD];
  const f32x4 fz4 = {0.f, 0.f, 0.f, 0.f};
  int tid = threadIdx.x;
  int d0 = blockIdx.x * 128;
  int y0 = blockIdx.y * 128;
  int b = blockIdx.z;
  const float* Ap = alpha + ((size_t)b * YQ + y0) * SQ;
  const ushort* Af = abf + ((size_t)b * YQ + y0) * SQ;
  const ushort* Bp = xT + ((size_t)b * DQ + d0) * SQ;
  f32x4 acc[4][4];
  #pragma unroll
  for (int i = 0; i < 4; ++i)
    #pragma unroll
    for (int j = 0; j < 4; ++j) acc[i][j] = fz4;
  int lane = tid & 63, wave = tid >> 6;
  int wm = wave & 1, wn = wave >> 1;
  int lr = lane & 15, lg = lane >> 4;

  for (int kc = 0; kc < SQ; kc += 128) {
    __syncthreads();
    #pragma unroll
    for (int it = 0; it < 8; ++it) {
      int gi = tid + it * 256;
      int r = gi >> 4, g = gi & 15;
      int y = y0 + r;
      int pofs = r * LD + swz_chunk(r, g) * 8;
      if (BF16A) {
        s16x8 a = {0, 0, 0, 0, 0, 0, 0, 0};
        if (y < YQ) a = *(const s16x8*)(Af + (size_t)r * SQ + kc + g * 8);
        *(s16x8*)&sA[pofs] = a;
      } else {
        ushort4 h0 = make_ushort4(0, 0, 0, 0), h1 = make_ushort4(0, 0, 0, 0);
        if (y < YQ) {
          f32x4 v0 = ld4u(Ap + (size_t)r * SQ + kc + g * 8);
          f32x4 v1 = ld4u(Ap + (size_t)r * SQ + kc + g * 8 + 4);
          h0 = make_ushort4(f2bf(v0.x), f2bf(v0.y), f2bf(v0.z), f2bf(v0.w));
          h1 = make_ushort4(f2bf(v1.x), f2bf(v1.y), f2bf(v1.z), f2bf(v1.w));
        }
        *(ushort4*)&sA[pofs] = h0;
        *(ushort4*)&sA[pofs + 4] = h1;
      }
      *(s16x8*)&sB[pofs] = *(const s16x8*)(Bp + (size_t)r * SQ + kc + g * 8);
    }
    __syncthreads();
    #pragma unroll
    for (int ks = 0; ks < 4; ++ks) {
      s16x8 af[4], bfr[4];
      #pragma unroll
      for (int i = 0; i < 4; ++i) {
        int row = wm * 64 + i * 16 + lr;
        af[i] = *(const s16x8*)&sA[row * LD + swz_chunk(row, ks * 4 + lg) * 8];
      }
      #pragma unroll
      for (int i = 0; i < 4; ++i) {
        int row = wn * 64 + i * 16 + lr;
        bfr[i] = *(const s16x8*)&sB[row * LD + swz_chunk(row, ks * 4 + lg) * 8];
      }
      #pragma unroll
      for (int i = 0; i < 4; ++i)
        #pragma unroll
        for (int j = 0; j < 4; ++j)
          acc[i][j] = mfma16(af[i], bfr[j], acc[i][j]);
    }
  }
  float* out = mo + (size_t)b * YQ * DQ;
  int rb = wm * 64 + lg * 4;
  int cb_ = wn * 64 + lr;
  #pragma unroll
  for (int i = 0; i < 4; ++i)
    #pragma unroll
    for (int j = 0; j < 4; ++j) {
      int col = d0 + cb_ + j * 16;
      #pragma unroll
      for (int q = 0; q < 4; ++q) {
        int r = y0 + rb + i * 16 + q;
        if (r < YQ) out[(size_t)r * DQ + col] = acc[i][j][q];
      }
    }
}

// ---------------- y = m . final_w + b ; BCE loss accumulate -----------------
__global__ void k_final(const float* __restrict__ m_in, const float* __restrict__ fw,
                        const float* __restrict__ fb, const float* __restrict__ tgt,
                        float* __restrict__ yo, float* __restrict__ lacc) {
  int y = blockIdx.x;
  int lane = threadIdx.x & 63;
  int b = threadIdx.x >> 6;      // 4 waves = 4 batches
  const float* mp = m_in + ((size_t)b * YQ + y) * DQ;
  const float* wp = fw + (size_t)y * DQ;
  float s = 0.f;
  #pragma unroll
  for (int i = 0; i < 8; ++i) {
    int e = lane + i * 64;
    s += mp[e] * wp[e];
  }
  #pragma unroll
  for (int o = 32; o > 0; o >>= 1) s += __shfl_xor(s, o);
  if (lane == 0) {
    float yv = s + fb[y];
    yo[(size_t)b * YQ + y] = yv;
    float t = tgt[(size_t)b * YQ + y];
    float l = fmaxf(yv, 0.f) - yv * t + log1pf(__expf(-fabsf(yv)));
    atomicAdd(lacc, l);
  }
}

__global__ void k_loss_fin(const float* __restrict__ lacc, float* __restrict__ out) {
  out[0] = lacc[0] * (1.0f / (float)(BQ * YQ));
}

extern "C" void kernel_launch(void* const* d_in, const int* in_sizes, int n_in,
                              void* d_out, int out_size, void* d_ws, size_t ws_size,
                              hipStream_t stream) {
  const float* x      = (const float*)d_in[0];
  const float* target = (const float*)d_in[1];
  const int*   c2t    = (const int*)d_in[2];
  const float* embed  = (const float*)d_in[3];
  const float* cw     = (const float*)d_in[4];
  const float* cb     = (const float*)d_in[5];
  const float* fw     = (const float*)d_in[6];
  const float* fb     = (const float*)d_in[7];

  char* ws = (char*)d_ws;
  ushort* xb = (ushort*)(ws);                   //  8,388,608 B
  ushort* xT = (ushort*)(ws + 8388608);         //  8,388,608 B
  ushort* Wp = (ushort*)(ws + 16777216);        //  1,179,648 B
  ushort* U  = (ushort*)(ws + 17956864);        //  9,175,040 B (YPAD x D bf16)
  float* lacc = (float*)(ws + 27131904);        //  4 B
  // optional bf16 alpha copy: 146,227,200 B
  const size_t ABF_OFF = 27262976;
  const size_t ABF_END = ABF_OFF + (size_t)BQ * YQ * SQ * 2;
  bool use_abf = (ws_size >= ABF_END);
  ushort* abf = use_abf ? (ushort*)(ws + ABF_OFF) : (ushort*)0;

  float* out       = (float*)d_out;
  float* out_y     = out;                               // [B][Y]
  float* out_loss  = out + (size_t)BQ * YQ;             // scalar
  float* out_alpha = out + (size_t)BQ * YQ + 1;         // [B][Y][S]
  float* out_m     = out_alpha + (size_t)BQ * YQ * SQ;  // [B][Y][D]

  hipMemsetAsync(U, 0, (size_t)YPAD * DQ * 2, stream);
  hipMemsetAsync(lacc, 0, 4, stream);

  k_prep_x<<<dim3(SQ / 32, DQ / 32, BQ), dim3(32, 32), 0, stream>>>(x, xb, xT);
  k_pack_w<<<dim3((KQ * DQ * EP + 255) / 256), 256, 0, stream>>>(cw, Wp);
  k_conv<<<dim3(4, (YQ + 3) / 4), 256, 0, stream>>>(c2t, embed, Wp, cb, U);
  k_scores<<<dim3(SQ / 128, (YQ + 127) / 128, BQ), 256, 0, stream>>>(U, xb, out_alpha);
  k_softmax<<<dim3(BQ * YQ), 256, 0, stream>>>(out_alpha, abf);
  if (use_abf)
    k_pv<true><<<dim3(DQ / 128, (YQ + 127) / 128, BQ), 256, 0, stream>>>(out_alpha, abf, xT, out_m);
  else
    k_pv<false><<<dim3(DQ / 128, (YQ + 127) / 128, BQ), 256, 0, stream>>>(out_alpha, abf, xT, out_m);
  k_final<<<dim3(YQ), 256, 0, stream>>>(out_m, fw, fb, target, out_y, lacc);
  k_loss_fin<<<1, 1, 0, stream>>>(lacc, out_loss);
}

// Round 3
// 1441.738 us; speedup vs baseline: 1.3427x; 1.3042x over previous
//
#include <hip/hip_runtime.h>
#include <math.h>

#define BQ 4
#define SQ 2048
#define DQ 512
#define YQ 8922
#define TQ 32
#define EQ 100
#define EP 128      // E padded for MFMA K-steps
#define KQ 9
#define LD 128      // LDS leading dim (bf16 elems) = 256B rows, XOR-swizzled
#define YPAD 8960   // U rows padded to multiple of 128

typedef float f32x4 __attribute__((ext_vector_type(4)));
typedef short s16x8 __attribute__((ext_vector_type(8)));

static __device__ __forceinline__ f32x4 mfma16(s16x8 a, s16x8 b, f32x4 c) {
  return __builtin_amdgcn_mfma_f32_16x16x32_bf16(a, b, c, 0, 0, 0);
}

static __device__ __forceinline__ ushort f2bf(float f) {
  union { float f; unsigned u; } v; v.f = f;
  unsigned r = (v.u + 0x7FFFu + ((v.u >> 16) & 1u)) >> 16;
  return (ushort)r;
}

// unaligned (4B) 16-byte load
static __device__ __forceinline__ f32x4 ld4u(const float* p) {
  f32x4 v; __builtin_memcpy(&v, p, 16); return v;
}

// T2 swizzle, full 4-bit: 16B-chunk index XOR'd with row&15.
// 16-lane frag-read group covers 16 DISTINCT chunks -> conflict-free at any
// granularity (the &7 variant left 4-way aliasing at half-wave; R2 counter
// proved it: 3.15e8 conflicts unchanged).
static __device__ __forceinline__ int swz_chunk(int row, int chunk) {
  return chunk ^ (row & 15);
}

// ---------------- prep: x -> bf16 [B][S][D] and transposed bf16 [B][D][S] ----
__global__ void k_prep_x(const float* __restrict__ x, ushort* __restrict__ xb,
                         ushort* __restrict__ xT) {
  __shared__ ushort sm[32][33];
  int b = blockIdx.z;
  int s0 = blockIdx.x * 32;
  int d0 = blockIdx.y * 32;
  int tx = threadIdx.x, ty = threadIdx.y;
  float v = x[((size_t)b * SQ + s0 + ty) * DQ + d0 + tx];
  ushort h = f2bf(v);
  xb[((size_t)b * SQ + s0 + ty) * DQ + d0 + tx] = h;
  sm[ty][tx] = h;
  __syncthreads();
  xT[((size_t)b * DQ + d0 + ty) * SQ + s0 + tx] = sm[tx][ty];
}

// ---------------- pack conv_w [D][E][K] -> Wp bf16 [K][D][EP] (e>=100 -> 0) --
__global__ void k_pack_w(const float* __restrict__ cw, ushort* __restrict__ Wp) {
  int i = blockIdx.x * 256 + threadIdx.x;
  if (i >= KQ * DQ * EP) return;
  int e = i & (EP - 1);
  int d = (i >> 7) & (DQ - 1);
  int kk = i >> 16;
  float v = (e < EQ) ? cw[((size_t)d * EQ + e) * KQ + kk] : 0.f;
  Wp[i] = f2bf(v);
}

// ---------------- conv + maxpool + tanh + scale -> U bf16 [YQ][D] -----------
__launch_bounds__(256, 2)
__global__ void k_conv(const int* __restrict__ c2t, const float* __restrict__ embed,
                       const ushort* __restrict__ Wp, const float* __restrict__ cb,
                       ushort* __restrict__ U) {
  __shared__ ushort sA[4 * TQ * LD];   // 32 KB: 4 labels x 32 t x 128 e
  __shared__ ushort sB[128 * LD];      // 32 KB: 128 d x 128 e (one kk)
  const f32x4 fz4 = {0.f, 0.f, 0.f, 0.f};
  const s16x8 sz8 = {0, 0, 0, 0, 0, 0, 0, 0};
  int tid = threadIdx.x;
  int d0 = blockIdx.x * 128;
  int y0 = blockIdx.y * 4;
  int lane = tid & 63, wave = tid >> 6;
  int wm = wave & 1, wn = wave >> 1;
  int lr = lane & 15, lg = lane >> 4;

  // stage all title embeddings for 4 labels: [4*32] rows x [LD] bf16, swizzled
  {
    int row = tid >> 1;
    int half = tid & 1;
    int yl = row >> 5, t = row & 31;
    int y = y0 + yl;
    const float* src = 0;
    if (y < YQ) src = embed + (size_t)c2t[y * TQ + t] * EQ + half * 64;
    #pragma unroll
    for (int j = 0; j < 16; ++j) {
      int col = half * 64 + j * 4;
      f32x4 v = fz4;
      if (src != 0 && col + 4 <= EQ) v = *(const f32x4*)(src + j * 4);
      ushort4 h = make_ushort4(f2bf(v.x), f2bf(v.y), f2bf(v.z), f2bf(v.w));
      int pc = swz_chunk(row, col >> 3);
      *(ushort4*)&sA[row * LD + pc * 8 + (col & 7)] = h;
    }
  }

  // B prologue: kk=0 via registers (same path as the steady-state prefetch)
  s16x8 breg[8];
  {
    const ushort* src = Wp + (size_t)d0 * EP;
    #pragma unroll
    for (int it = 0; it < 8; ++it) {
      int gi = tid + it * 256, r = gi >> 4, g = gi & 15;
      breg[it] = *(const s16x8*)(src + (size_t)r * EP + g * 8);
    }
    #pragma unroll
    for (int it = 0; it < 8; ++it) {
      int gi = tid + it * 256, r = gi >> 4, g = gi & 15;
      *(s16x8*)&sB[r * LD + swz_chunk(r, g) * 8] = breg[it];
    }
  }
  __syncthreads();

  f32x4 acc[4][4];
  #pragma unroll
  for (int i = 0; i < 4; ++i)
    #pragma unroll
    for (int j = 0; j < 4; ++j) acc[i][j] = fz4;

  for (int kk = 0; kk < KQ; ++kk) {
    // T14: issue next-kk weight loads into regs BEFORE compute (latency hides
    // under the 64 MFMA + 32 ds_read of this kk)
    if (kk + 1 < KQ) {
      const ushort* src = Wp + ((size_t)(kk + 1) * DQ + d0) * EP;
      #pragma unroll
      for (int it = 0; it < 8; ++it) {
        int gi = tid + it * 256, r = gi >> 4, g = gi & 15;
        breg[it] = *(const s16x8*)(src + (size_t)r * EP + g * 8);
      }
    }
    #pragma unroll
    for (int ee = 0; ee < 4; ++ee) {
      s16x8 af[4], bfr[4];
      #pragma unroll
      for (int i = 0; i < 4; ++i) {
        int rowm = wm * 64 + i * 16 + lr;
        int yl = rowm >> 5;
        int ts = (rowm & 31) + kk - 4;   // shifted time index
        s16x8 a = sz8;
        if ((unsigned)ts < (unsigned)TQ) {
          int row = yl * TQ + ts;
          a = *(const s16x8*)&sA[row * LD + swz_chunk(row, ee * 4 + lg) * 8];
        }
        af[i] = a;
      }
      #pragma unroll
      for (int i = 0; i < 4; ++i) {
        int row = wn * 64 + i * 16 + lr;
        bfr[i] = *(const s16x8*)&sB[row * LD + swz_chunk(row, ee * 4 + lg) * 8];
      }
      #pragma unroll
      for (int i = 0; i < 4; ++i)
        #pragma unroll
        for (int j = 0; j < 4; ++j)
          acc[i][j] = mfma16(af[i], bfr[j], acc[i][j]);
    }
    __syncthreads();           // all waves done reading sB for this kk
    if (kk + 1 < KQ) {
      #pragma unroll
      for (int it = 0; it < 8; ++it) {
        int gi = tid + it * 256, r = gi >> 4, g = gi & 15;
        *(s16x8*)&sB[r * LD + swz_chunk(r, g) * 8] = breg[it];
      }
      __syncthreads();         // sB(kk+1) visible
    }
  }

  // in-register epilogue: maxpool over t via in-lane fmax + shfl, tanh, scale
  const float scl = 0.04419417382415922f;   // 1/sqrt(D)
  #pragma unroll
  for (int L2 = 0; L2 < 2; ++L2) {
    int y = y0 + wm * 2 + L2;
    #pragma unroll
    for (int j = 0; j < 4; ++j) {
      float mx = -3.0e38f;
      #pragma unroll
      for (int ii = 0; ii < 2; ++ii)
        #pragma unroll
        for (int q = 0; q < 4; ++q)
          mx = fmaxf(mx, acc[L2 * 2 + ii][j][q]);
      mx = fmaxf(mx, __shfl_xor(mx, 16));
      mx = fmaxf(mx, __shfl_xor(mx, 32));
      if (lane < 16 && y < YQ) {
        int col = d0 + wn * 64 + j * 16 + lane;
        U[(size_t)y * DQ + col] = f2bf(tanhf(mx + cb[col]) * scl);
      }
    }
  }
}

// ---------------- scores = U . xb^T -> raw scores into d_out alpha slot -----
__launch_bounds__(256, 2)
__global__ void k_scores(const ushort* __restrict__ U, const ushort* __restrict__ xb,
                         float* __restrict__ sc) {
  __shared__ ushort sA[128 * LD];
  __shared__ ushort sB[128 * LD];
  const f32x4 fz4 = {0.f, 0.f, 0.f, 0.f};
  int tid = threadIdx.x;
  int s0 = blockIdx.x * 128;
  int y0 = blockIdx.y * 128;
  int b = blockIdx.z;
  const ushort* Ap = U + (size_t)y0 * DQ;
  const ushort* Bp = xb + ((size_t)b * SQ + s0) * DQ;
  f32x4 acc[4][4];
  #pragma unroll
  for (int i = 0; i < 4; ++i)
    #pragma unroll
    for (int j = 0; j < 4; ++j) acc[i][j] = fz4;
  int lane = tid & 63, wave = tid >> 6;
  int wm = wave & 1, wn = wave >> 1;
  int lr = lane & 15, lg = lane >> 4;

  for (int kc = 0; kc < DQ; kc += 128) {
    __syncthreads();
    #pragma unroll
    for (int it = 0; it < 8; ++it) {
      int gi = tid + it * 256;
      int r = gi >> 4, g = gi & 15;
      int pofs = r * LD + swz_chunk(r, g) * 8;
      *(s16x8*)&sA[pofs] = *(const s16x8*)(Ap + (size_t)r * DQ + kc + g * 8);
      *(s16x8*)&sB[pofs] = *(const s16x8*)(Bp + (size_t)r * DQ + kc + g * 8);
    }
    __syncthreads();
    #pragma unroll
    for (int ks = 0; ks < 4; ++ks) {
      s16x8 af[4], bfr[4];
      #pragma unroll
      for (int i = 0; i < 4; ++i) {
        int row = wm * 64 + i * 16 + lr;
        af[i] = *(const s16x8*)&sA[row * LD + swz_chunk(row, ks * 4 + lg) * 8];
      }
      #pragma unroll
      for (int i = 0; i < 4; ++i) {
        int row = wn * 64 + i * 16 + lr;
        bfr[i] = *(const s16x8*)&sB[row * LD + swz_chunk(row, ks * 4 + lg) * 8];
      }
      #pragma unroll
      for (int i = 0; i < 4; ++i)
        #pragma unroll
        for (int j = 0; j < 4; ++j)
          acc[i][j] = mfma16(af[i], bfr[j], acc[i][j]);
    }
  }
  float* out = sc + (size_t)b * YQ * SQ;
  int rb = wm * 64 + lg * 4;
  int cb_ = wn * 64 + lr;
  #pragma unroll
  for (int i = 0; i < 4; ++i)
    #pragma unroll
    for (int j = 0; j < 4; ++j) {
      int col = s0 + cb_ + j * 16;
      #pragma unroll
      for (int q = 0; q < 4; ++q) {
        int r = y0 + rb + i * 16 + q;
        if (r < YQ) out[(size_t)r * SQ + col] = acc[i][j][q];
      }
    }
}

// ---- in-place softmax over S (one block per (b,y) row); optional bf16 copy --
__global__ void k_softmax(float* __restrict__ a, ushort* __restrict__ abf) {
  float* p = a + (size_t)blockIdx.x * SQ;
  int tid = threadIdx.x;
  int lane = tid & 63, wave = tid >> 6;
  float v[8];
  #pragma unroll
  for (int i = 0; i < 8; ++i) v[i] = p[tid + i * 256];
  float mx = v[0];
  #pragma unroll
  for (int i = 1; i < 8; ++i) mx = fmaxf(mx, v[i]);
  #pragma unroll
  for (int o = 32; o > 0; o >>= 1) mx = fmaxf(mx, __shfl_xor(mx, o));
  __shared__ float red[8];
  if (lane == 0) red[wave] = mx;
  __syncthreads();
  mx = fmaxf(fmaxf(red[0], red[1]), fmaxf(red[2], red[3]));
  float s = 0.f;
  #pragma unroll
  for (int i = 0; i < 8; ++i) { v[i] = __expf(v[i] - mx); s += v[i]; }
  #pragma unroll
  for (int o = 32; o > 0; o >>= 1) s += __shfl_xor(s, o);
  if (lane == 0) red[4 + wave] = s;
  __syncthreads();
  s = (red[4] + red[5]) + (red[6] + red[7]);
  float inv = 1.0f / s;
  ushort* q = abf ? abf + (size_t)blockIdx.x * SQ : 0;
  #pragma unroll
  for (int i = 0; i < 8; ++i) {
    float av = v[i] * inv;
    p[tid + i * 256] = av;
    if (q) q[tid + i * 256] = f2bf(av);
  }
}

// ---------------- m = alpha . x  (B-op = pre-transposed xT) -----------------
template <bool BF16A>
__launch_bounds__(256, 2)
__global__ void k_pv(const float* __restrict__ alpha, const ushort* __restrict__ abf,
                     const ushort* __restrict__ xT, float* __restrict__ mo) {
  __shared__ ushort sA[128 * LD];
  __shared__ ushort sB[128 * LD];
  const f32x4 fz4 = {0.f, 0.f, 0.f, 0.f};
  int tid = threadIdx.x;
  int d0 = blockIdx.x * 128;
  int y0 = blockIdx.y * 128;
  int b = blockIdx.z;
  const float* Ap = alpha + ((size_t)b * YQ + y0) * SQ;
  const ushort* Af = abf + ((size_t)b * YQ + y0) * SQ;
  const ushort* Bp = xT + ((size_t)b * DQ + d0) * SQ;
  f32x4 acc[4][4];
  #pragma unroll
  for (int i = 0; i < 4; ++i)
    #pragma unroll
    for (int j = 0; j < 4; ++j) acc[i][j] = fz4;
  int lane = tid & 63, wave = tid >> 6;
  int wm = wave & 1, wn = wave >> 1;
  int lr = lane & 15, lg = lane >> 4;

  for (int kc = 0; kc < SQ; kc += 128) {
    __syncthreads();
    #pragma unroll
    for (int it = 0; it < 8; ++it) {
      int gi = tid + it * 256;
      int r = gi >> 4, g = gi & 15;
      int y = y0 + r;
      int pofs = r * LD + swz_chunk(r, g) * 8;
      if (BF16A) {
        s16x8 a = {0, 0, 0, 0, 0, 0, 0, 0};
        if (y < YQ) a = *(const s16x8*)(Af + (size_t)r * SQ + kc + g * 8);
        *(s16x8*)&sA[pofs] = a;
      } else {
        ushort4 h0 = make_ushort4(0, 0, 0, 0), h1 = make_ushort4(0, 0, 0, 0);
        if (y < YQ) {
          f32x4 v0 = ld4u(Ap + (size_t)r * SQ + kc + g * 8);
          f32x4 v1 = ld4u(Ap + (size_t)r * SQ + kc + g * 8 + 4);
          h0 = make_ushort4(f2bf(v0.x), f2bf(v0.y), f2bf(v0.z), f2bf(v0.w));
          h1 = make_ushort4(f2bf(v1.x), f2bf(v1.y), f2bf(v1.z), f2bf(v1.w));
        }
        *(ushort4*)&sA[pofs] = h0;
        *(ushort4*)&sA[pofs + 4] = h1;
      }
      *(s16x8*)&sB[pofs] = *(const s16x8*)(Bp + (size_t)r * SQ + kc + g * 8);
    }
    __syncthreads();
    #pragma unroll
    for (int ks = 0; ks < 4; ++ks) {
      s16x8 af[4], bfr[4];
      #pragma unroll
      for (int i = 0; i < 4; ++i) {
        int row = wm * 64 + i * 16 + lr;
        af[i] = *(const s16x8*)&sA[row * LD + swz_chunk(row, ks * 4 + lg) * 8];
      }
      #pragma unroll
      for (int i = 0; i < 4; ++i) {
        int row = wn * 64 + i * 16 + lr;
        bfr[i] = *(const s16x8*)&sB[row * LD + swz_chunk(row, ks * 4 + lg) * 8];
      }
      #pragma unroll
      for (int i = 0; i < 4; ++i)
        #pragma unroll
        for (int j = 0; j < 4; ++j)
          acc[i][j] = mfma16(af[i], bfr[j], acc[i][j]);
    }
  }
  float* out = mo + (size_t)b * YQ * DQ;
  int rb = wm * 64 + lg * 4;
  int cb_ = wn * 64 + lr;
  #pragma unroll
  for (int i = 0; i < 4; ++i)
    #pragma unroll
    for (int j = 0; j < 4; ++j) {
      int col = d0 + cb_ + j * 16;
      #pragma unroll
      for (int q = 0; q < 4; ++q) {
        int r = y0 + rb + i * 16 + q;
        if (r < YQ) out[(size_t)r * DQ + col] = acc[i][j][q];
      }
    }
}

// ---------------- y = m . final_w + b ; BCE loss accumulate -----------------
__global__ void k_final(const float* __restrict__ m_in, const float* __restrict__ fw,
                        const float* __restrict__ fb, const float* __restrict__ tgt,
                        float* __restrict__ yo, float* __restrict__ lacc) {
  int y = blockIdx.x;
  int lane = threadIdx.x & 63;
  int b = threadIdx.x >> 6;      // 4 waves = 4 batches
  const float* mp = m_in + ((size_t)b * YQ + y) * DQ;
  const float* wp = fw + (size_t)y * DQ;
  float s = 0.f;
  #pragma unroll
  for (int i = 0; i < 8; ++i) {
    int e = lane + i * 64;
    s += mp[e] * wp[e];
  }
  #pragma unroll
  for (int o = 32; o > 0; o >>= 1) s += __shfl_xor(s, o);
  if (lane == 0) {
    float yv = s + fb[y];
    yo[(size_t)b * YQ + y] = yv;
    float t = tgt[(size_t)b * YQ + y];
    float l = fmaxf(yv, 0.f) - yv * t + log1pf(__expf(-fabsf(yv)));
    atomicAdd(lacc, l);
  }
}

__global__ void k_loss_fin(const float* __restrict__ lacc, float* __restrict__ out) {
  out[0] = lacc[0] * (1.0f / (float)(BQ * YQ));
}

extern "C" void kernel_launch(void* const* d_in, const int* in_sizes, int n_in,
                              void* d_out, int out_size, void* d_ws, size_t ws_size,
                              hipStream_t stream) {
  const float* x      = (const float*)d_in[0];
  const float* target = (const float*)d_in[1];
  const int*   c2t    = (const int*)d_in[2];
  const float* embed  = (const float*)d_in[3];
  const float* cw     = (const float*)d_in[4];
  const float* cb     = (const float*)d_in[5];
  const float* fw     = (const float*)d_in[6];
  const float* fb     = (const float*)d_in[7];

  char* ws = (char*)d_ws;
  ushort* xb = (ushort*)(ws);                   //  8,388,608 B
  ushort* xT = (ushort*)(ws + 8388608);         //  8,388,608 B
  ushort* Wp = (ushort*)(ws + 16777216);        //  1,179,648 B
  ushort* U  = (ushort*)(ws + 17956864);        //  9,175,040 B (YPAD x D bf16)
  float* lacc = (float*)(ws + 27131904);        //  4 B
  // optional bf16 alpha copy: 146,227,200 B
  const size_t ABF_OFF = 27262976;
  const size_t ABF_END = ABF_OFF + (size_t)BQ * YQ * SQ * 2;
  bool use_abf = (ws_size >= ABF_END);
  ushort* abf = use_abf ? (ushort*)(ws + ABF_OFF) : (ushort*)0;

  float* out       = (float*)d_out;
  float* out_y     = out;                               // [B][Y]
  float* out_loss  = out + (size_t)BQ * YQ;             // scalar
  float* out_alpha = out + (size_t)BQ * YQ + 1;         // [B][Y][S]
  float* out_m     = out_alpha + (size_t)BQ * YQ * SQ;  // [B][Y][D]

  hipMemsetAsync(U, 0, (size_t)YPAD * DQ * 2, stream);
  hipMemsetAsync(lacc, 0, 4, stream);

  k_prep_x<<<dim3(SQ / 32, DQ / 32, BQ), dim3(32, 32), 0, stream>>>(x, xb, xT);
  k_pack_w<<<dim3((KQ * DQ * EP + 255) / 256), 256, 0, stream>>>(cw, Wp);
  k_conv<<<dim3(4, (YQ + 3) / 4), 256, 0, stream>>>(c2t, embed, Wp, cb, U);
  k_scores<<<dim3(SQ / 128, (YQ + 127) / 128, BQ), 256, 0, stream>>>(U, xb, out_alpha);
  k_softmax<<<dim3(BQ * YQ), 256, 0, stream>>>(out_alpha, abf);
  if (use_abf)
    k_pv<true><<<dim3(DQ / 128, (YQ + 127) / 128, BQ), 256, 0, stream>>>(out_alpha, abf, xT, out_m);
  else
    k_pv<false><<<dim3(DQ / 128, (YQ + 127) / 128, BQ), 256, 0, stream>>>(out_alpha, abf, xT, out_m);
  k_final<<<dim3(YQ), 256, 0, stream>>>(out_m, fw, fb, target, out_y, lacc);
  k_loss_fin<<<1, 1, 0, stream>>>(lacc, out_loss);
}

// Round 4
// 1014.390 us; speedup vs baseline: 1.9084x; 1.4213x over previous
//
#include <hip/hip_runtime.h>
#include <math.h>

#define BQ 4
#define SQ 2048
#define DQ 512
#define YQ 8922
#define TQ 32
#define EQ 100
#define EP 128      // E padded for MFMA K-steps
#define KQ 9
#define LD 128      // LDS leading dim (bf16 elems) = 256B rows, XOR-swizzled
#define YPAD 8960   // U rows padded to multiple of 128

typedef float f32x4 __attribute__((ext_vector_type(4)));
typedef short s16x8 __attribute__((ext_vector_type(8)));

static __device__ __forceinline__ f32x4 mfma16(s16x8 a, s16x8 b, f32x4 c) {
  return __builtin_amdgcn_mfma_f32_16x16x32_bf16(a, b, c, 0, 0, 0);
}

static __device__ __forceinline__ ushort f2bf(float f) {
  union { float f; unsigned u; } v; v.f = f;
  unsigned r = (v.u + 0x7FFFu + ((v.u >> 16) & 1u)) >> 16;
  return (ushort)r;
}

// unaligned (4B) 16-byte load
static __device__ __forceinline__ f32x4 ld4u(const float* p) {
  f32x4 v; __builtin_memcpy(&v, p, 16); return v;
}

// T2 swizzle, full 4-bit: 16B-chunk index XOR'd with row&15.
// (R2->R3: &7 left 4-way aliasing, 3.15e8 conflicts; &15 fixed it.)
static __device__ __forceinline__ int swz_chunk(int row, int chunk) {
  return chunk ^ (row & 15);
}

// ---------------- prep: x -> bf16 [B][S][D] and transposed bf16 [B][D][S] ----
__global__ void k_prep_x(const float* __restrict__ x, ushort* __restrict__ xb,
                         ushort* __restrict__ xT) {
  __shared__ ushort sm[32][33];
  int b = blockIdx.z;
  int s0 = blockIdx.x * 32;
  int d0 = blockIdx.y * 32;
  int tx = threadIdx.x, ty = threadIdx.y;
  float v = x[((size_t)b * SQ + s0 + ty) * DQ + d0 + tx];
  ushort h = f2bf(v);
  xb[((size_t)b * SQ + s0 + ty) * DQ + d0 + tx] = h;
  sm[ty][tx] = h;
  __syncthreads();
  xT[((size_t)b * DQ + d0 + ty) * SQ + s0 + tx] = sm[tx][ty];
}

// ---------------- pack conv_w [D][E][K] -> Wp bf16 [K][D][EP] (e>=100 -> 0) --
__global__ void k_pack_w(const float* __restrict__ cw, ushort* __restrict__ Wp) {
  int i = blockIdx.x * 256 + threadIdx.x;
  if (i >= KQ * DQ * EP) return;
  int e = i & (EP - 1);
  int d = (i >> 7) & (DQ - 1);
  int kk = i >> 16;
  float v = (e < EQ) ? cw[((size_t)d * EQ + e) * KQ + kk] : 0.f;
  Wp[i] = f2bf(v);
}

// ---------------- conv + maxpool + tanh + scale -> U bf16 [YQ][D] -----------
__launch_bounds__(256, 2)
__global__ void k_conv(const int* __restrict__ c2t, const float* __restrict__ embed,
                       const ushort* __restrict__ Wp, const float* __restrict__ cb,
                       ushort* __restrict__ U) {
  __shared__ ushort sA[4 * TQ * LD];   // 32 KB: 4 labels x 32 t x 128 e
  __shared__ ushort sB[128 * LD];      // 32 KB: 128 d x 128 e (one kk)
  const f32x4 fz4 = {0.f, 0.f, 0.f, 0.f};
  const s16x8 sz8 = {0, 0, 0, 0, 0, 0, 0, 0};
  int tid = threadIdx.x;
  int d0 = blockIdx.x * 128;
  int y0 = blockIdx.y * 4;
  int lane = tid & 63, wave = tid >> 6;
  int wm = wave & 1, wn = wave >> 1;
  int lr = lane & 15, lg = lane >> 4;

  // stage all title embeddings for 4 labels: [4*32] rows x [LD] bf16, swizzled
  {
    int row = tid >> 1;
    int half = tid & 1;
    int yl = row >> 5, t = row & 31;
    int y = y0 + yl;
    const float* src = 0;
    if (y < YQ) src = embed + (size_t)c2t[y * TQ + t] * EQ + half * 64;
    #pragma unroll
    for (int j = 0; j < 16; ++j) {
      int col = half * 64 + j * 4;
      f32x4 v = fz4;
      if (src != 0 && col + 4 <= EQ) v = *(const f32x4*)(src + j * 4);
      ushort4 h = make_ushort4(f2bf(v.x), f2bf(v.y), f2bf(v.z), f2bf(v.w));
      int pc = swz_chunk(row, col >> 3);
      *(ushort4*)&sA[row * LD + pc * 8 + (col & 7)] = h;
    }
  }

  // B prologue: kk=0 via registers (same path as the steady-state prefetch)
  s16x8 breg[8];
  {
    const ushort* src = Wp + (size_t)d0 * EP;
    #pragma unroll
    for (int it = 0; it < 8; ++it) {
      int gi = tid + it * 256, r = gi >> 4, g = gi & 15;
      breg[it] = *(const s16x8*)(src + (size_t)r * EP + g * 8);
    }
    #pragma unroll
    for (int it = 0; it < 8; ++it) {
      int gi = tid + it * 256, r = gi >> 4, g = gi & 15;
      *(s16x8*)&sB[r * LD + swz_chunk(r, g) * 8] = breg[it];
    }
  }
  __syncthreads();

  f32x4 acc[4][4];
  #pragma unroll
  for (int i = 0; i < 4; ++i)
    #pragma unroll
    for (int j = 0; j < 4; ++j) acc[i][j] = fz4;

  for (int kk = 0; kk < KQ; ++kk) {
    // T14: issue next-kk weight loads into regs BEFORE compute
    if (kk + 1 < KQ) {
      const ushort* src = Wp + ((size_t)(kk + 1) * DQ + d0) * EP;
      #pragma unroll
      for (int it = 0; it < 8; ++it) {
        int gi = tid + it * 256, r = gi >> 4, g = gi & 15;
        breg[it] = *(const s16x8*)(src + (size_t)r * EP + g * 8);
      }
    }
    #pragma unroll
    for (int ee = 0; ee < 4; ++ee) {
      s16x8 af[4], bfr[4];
      #pragma unroll
      for (int i = 0; i < 4; ++i) {
        int rowm = wm * 64 + i * 16 + lr;
        int yl = rowm >> 5;
        int ts = (rowm & 31) + kk - 4;   // shifted time index
        s16x8 a = sz8;
        if ((unsigned)ts < (unsigned)TQ) {
          int row = yl * TQ + ts;
          a = *(const s16x8*)&sA[row * LD + swz_chunk(row, ee * 4 + lg) * 8];
        }
        af[i] = a;
      }
      #pragma unroll
      for (int i = 0; i < 4; ++i) {
        int row = wn * 64 + i * 16 + lr;
        bfr[i] = *(const s16x8*)&sB[row * LD + swz_chunk(row, ee * 4 + lg) * 8];
      }
      #pragma unroll
      for (int i = 0; i < 4; ++i)
        #pragma unroll
        for (int j = 0; j < 4; ++j)
          acc[i][j] = mfma16(af[i], bfr[j], acc[i][j]);
    }
    __syncthreads();           // all waves done reading sB for this kk
    if (kk + 1 < KQ) {
      #pragma unroll
      for (int it = 0; it < 8; ++it) {
        int gi = tid + it * 256, r = gi >> 4, g = gi & 15;
        *(s16x8*)&sB[r * LD + swz_chunk(r, g) * 8] = breg[it];
      }
      __syncthreads();         // sB(kk+1) visible
    }
  }

  // in-register epilogue: maxpool over t via in-lane fmax + shfl, tanh, scale
  const float scl = 0.04419417382415922f;   // 1/sqrt(D)
  #pragma unroll
  for (int L2 = 0; L2 < 2; ++L2) {
    int y = y0 + wm * 2 + L2;
    #pragma unroll
    for (int j = 0; j < 4; ++j) {
      float mx = -3.0e38f;
      #pragma unroll
      for (int ii = 0; ii < 2; ++ii)
        #pragma unroll
        for (int q = 0; q < 4; ++q)
          mx = fmaxf(mx, acc[L2 * 2 + ii][j][q]);
      mx = fmaxf(mx, __shfl_xor(mx, 16));
      mx = fmaxf(mx, __shfl_xor(mx, 32));
      if (lane < 16 && y < YQ) {
        int col = d0 + wn * 64 + j * 16 + lane;
        U[(size_t)y * DQ + col] = f2bf(tanhf(mx + cb[col]) * scl);
      }
    }
  }
}

// ---------------- scores = U . xb^T -> raw scores into d_out alpha slot -----
__launch_bounds__(256, 2)
__global__ void k_scores(const ushort* __restrict__ U, const ushort* __restrict__ xb,
                         float* __restrict__ sc) {
  __shared__ ushort sA[128 * LD];
  __shared__ ushort sB[128 * LD];
  const f32x4 fz4 = {0.f, 0.f, 0.f, 0.f};
  int tid = threadIdx.x;
  int s0 = blockIdx.x * 128;
  int y0 = blockIdx.y * 128;
  int b = blockIdx.z;
  const ushort* Ap = U + (size_t)y0 * DQ;
  const ushort* Bp = xb + ((size_t)b * SQ + s0) * DQ;
  f32x4 acc[4][4];
  #pragma unroll
  for (int i = 0; i < 4; ++i)
    #pragma unroll
    for (int j = 0; j < 4; ++j) acc[i][j] = fz4;
  int lane = tid & 63, wave = tid >> 6;
  int wm = wave & 1, wn = wave >> 1;
  int lr = lane & 15, lg = lane >> 4;

  for (int kc = 0; kc < DQ; kc += 128) {
    __syncthreads();
    #pragma unroll
    for (int it = 0; it < 8; ++it) {
      int gi = tid + it * 256;
      int r = gi >> 4, g = gi & 15;
      int pofs = r * LD + swz_chunk(r, g) * 8;
      *(s16x8*)&sA[pofs] = *(const s16x8*)(Ap + (size_t)r * DQ + kc + g * 8);
      *(s16x8*)&sB[pofs] = *(const s16x8*)(Bp + (size_t)r * DQ + kc + g * 8);
    }
    __syncthreads();
    #pragma unroll
    for (int ks = 0; ks < 4; ++ks) {
      s16x8 af[4], bfr[4];
      #pragma unroll
      for (int i = 0; i < 4; ++i) {
        int row = wm * 64 + i * 16 + lr;
        af[i] = *(const s16x8*)&sA[row * LD + swz_chunk(row, ks * 4 + lg) * 8];
      }
      #pragma unroll
      for (int i = 0; i < 4; ++i) {
        int row = wn * 64 + i * 16 + lr;
        bfr[i] = *(const s16x8*)&sB[row * LD + swz_chunk(row, ks * 4 + lg) * 8];
      }
      #pragma unroll
      for (int i = 0; i < 4; ++i)
        #pragma unroll
        for (int j = 0; j < 4; ++j)
          acc[i][j] = mfma16(af[i], bfr[j], acc[i][j]);
    }
  }
  float* out = sc + (size_t)b * YQ * SQ;
  int rb = wm * 64 + lg * 4;
  int cb_ = wn * 64 + lr;
  #pragma unroll
  for (int i = 0; i < 4; ++i)
    #pragma unroll
    for (int j = 0; j < 4; ++j) {
      int col = s0 + cb_ + j * 16;
      #pragma unroll
      for (int q = 0; q < 4; ++q) {
        int r = y0 + rb + i * 16 + q;
        if (r < YQ) out[(size_t)r * SQ + col] = acc[i][j][q];
      }
    }
}

// ---- in-place softmax over S (one block per (b,y) row); optional bf16 copy --
__global__ void k_softmax(float* __restrict__ a, ushort* __restrict__ abf) {
  float* p = a + (size_t)blockIdx.x * SQ;
  int tid = threadIdx.x;
  int lane = tid & 63, wave = tid >> 6;
  float v[8];
  #pragma unroll
  for (int i = 0; i < 8; ++i) v[i] = p[tid + i * 256];
  float mx = v[0];
  #pragma unroll
  for (int i = 1; i < 8; ++i) mx = fmaxf(mx, v[i]);
  #pragma unroll
  for (int o = 32; o > 0; o >>= 1) mx = fmaxf(mx, __shfl_xor(mx, o));
  __shared__ float red[8];
  if (lane == 0) red[wave] = mx;
  __syncthreads();
  mx = fmaxf(fmaxf(red[0], red[1]), fmaxf(red[2], red[3]));
  float s = 0.f;
  #pragma unroll
  for (int i = 0; i < 8; ++i) { v[i] = __expf(v[i] - mx); s += v[i]; }
  #pragma unroll
  for (int o = 32; o > 0; o >>= 1) s += __shfl_xor(s, o);
  if (lane == 0) red[4 + wave] = s;
  __syncthreads();
  s = (red[4] + red[5]) + (red[6] + red[7]);
  float inv = 1.0f / s;
  ushort* q = abf ? abf + (size_t)blockIdx.x * SQ : 0;
  #pragma unroll
  for (int i = 0; i < 8; ++i) {
    float av = v[i] * inv;
    p[tid + i * 256] = av;
    if (q) q[tid + i * 256] = f2bf(av);
  }
}

// ---------------- m = alpha . x  (B-op = pre-transposed xT) -----------------
template <bool BF16A>
__launch_bounds__(256, 2)
__global__ void k_pv(const float* __restrict__ alpha, const ushort* __restrict__ abf,
                     const ushort* __restrict__ xT, float* __restrict__ mo) {
  __shared__ ushort sA[128 * LD];
  __shared__ ushort sB[128 * LD];
  const f32x4 fz4 = {0.f, 0.f, 0.f, 0.f};
  int tid = threadIdx.x;
  int d0 = blockIdx.x * 128;
  int y0 = blockIdx.y * 128;
  int b = blockIdx.z;
  const float* Ap = alpha + ((size_t)b * YQ + y0) * SQ;
  const ushort* Af = abf + ((size_t)b * YQ + y0) * SQ;
  const ushort* Bp = xT + ((size_t)b * DQ + d0) * SQ;
  f32x4 acc[4][4];
  #pragma unroll
  for (int i = 0; i < 4; ++i)
    #pragma unroll
    for (int j = 0; j < 4; ++j) acc[i][j] = fz4;
  int lane = tid & 63, wave = tid >> 6;
  int wm = wave & 1, wn = wave >> 1;
  int lr = lane & 15, lg = lane >> 4;

  for (int kc = 0; kc < SQ; kc += 128) {
    __syncthreads();
    #pragma unroll
    for (int it = 0; it < 8; ++it) {
      int gi = tid + it * 256;
      int r = gi >> 4, g = gi & 15;
      int y = y0 + r;
      int pofs = r * LD + swz_chunk(r, g) * 8;
      if (BF16A) {
        s16x8 a = {0, 0, 0, 0, 0, 0, 0, 0};
        if (y < YQ) a = *(const s16x8*)(Af + (size_t)r * SQ + kc + g * 8);
        *(s16x8*)&sA[pofs] = a;
      } else {
        ushort4 h0 = make_ushort4(0, 0, 0, 0), h1 = make_ushort4(0, 0, 0, 0);
        if (y < YQ) {
          f32x4 v0 = ld4u(Ap + (size_t)r * SQ + kc + g * 8);
          f32x4 v1 = ld4u(Ap + (size_t)r * SQ + kc + g * 8 + 4);
          h0 = make_ushort4(f2bf(v0.x), f2bf(v0.y), f2bf(v0.z), f2bf(v0.w));
          h1 = make_ushort4(f2bf(v1.x), f2bf(v1.y), f2bf(v1.z), f2bf(v1.w));
        }
        *(ushort4*)&sA[pofs] = h0;
        *(ushort4*)&sA[pofs + 4] = h1;
      }
      *(s16x8*)&sB[pofs] = *(const s16x8*)(Bp + (size_t)r * SQ + kc + g * 8);
    }
    __syncthreads();
    #pragma unroll
    for (int ks = 0; ks < 4; ++ks) {
      s16x8 af[4], bfr[4];
      #pragma unroll
      for (int i = 0; i < 4; ++i) {
        int row = wm * 64 + i * 16 + lr;
        af[i] = *(const s16x8*)&sA[row * LD + swz_chunk(row, ks * 4 + lg) * 8];
      }
      #pragma unroll
      for (int i = 0; i < 4; ++i) {
        int row = wn * 64 + i * 16 + lr;
        bfr[i] = *(const s16x8*)&sB[row * LD + swz_chunk(row, ks * 4 + lg) * 8];
      }
      #pragma unroll
      for (int i = 0; i < 4; ++i)
        #pragma unroll
        for (int j = 0; j < 4; ++j)
          acc[i][j] = mfma16(af[i], bfr[j], acc[i][j]);
    }
  }
  float* out = mo + (size_t)b * YQ * DQ;
  int rb = wm * 64 + lg * 4;
  int cb_ = wn * 64 + lr;
  #pragma unroll
  for (int i = 0; i < 4; ++i)
    #pragma unroll
    for (int j = 0; j < 4; ++j) {
      int col = d0 + cb_ + j * 16;
      #pragma unroll
      for (int q = 0; q < 4; ++q) {
        int r = y0 + rb + i * 16 + q;
        if (r < YQ) out[(size_t)r * DQ + col] = acc[i][j][q];
      }
    }
}

// ------- y = m . final_w + b ; per-block loss partial (NO hot atomics) ------
__global__ void k_final(const float* __restrict__ m_in, const float* __restrict__ fw,
                        const float* __restrict__ fb, const float* __restrict__ tgt,
                        float* __restrict__ yo, float* __restrict__ part) {
  int y = blockIdx.x;
  int lane = threadIdx.x & 63;
  int b = threadIdx.x >> 6;      // 4 waves = 4 batches
  const float* mp = m_in + ((size_t)b * YQ + y) * DQ;
  const float* wp = fw + (size_t)y * DQ;
  float s = 0.f;
  #pragma unroll
  for (int i = 0; i < 8; ++i) {
    int e = lane + i * 64;
    s += mp[e] * wp[e];
  }
  #pragma unroll
  for (int o = 32; o > 0; o >>= 1) s += __shfl_xor(s, o);
  __shared__ float pl[4];
  if (lane == 0) {
    float yv = s + fb[y];
    yo[(size_t)b * YQ + y] = yv;
    float t = tgt[(size_t)b * YQ + y];
    pl[b] = fmaxf(yv, 0.f) - yv * t + log1pf(__expf(-fabsf(yv)));
  }
  __syncthreads();
  if (threadIdx.x == 0)
    part[y] = (pl[0] + pl[1]) + (pl[2] + pl[3]);
}

// ------- reduce 8922 per-label partials -> mean loss ------------------------
__global__ void k_loss_fin(const float* __restrict__ part, float* __restrict__ out) {
  int tid = threadIdx.x;
  float s = 0.f;
  for (int i = tid; i < YQ; i += 256) s += part[i];
  #pragma unroll
  for (int o = 32; o > 0; o >>= 1) s += __shfl_xor(s, o);
  __shared__ float red[4];
  int lane = tid & 63, wave = tid >> 6;
  if (lane == 0) red[wave] = s;
  __syncthreads();
  if (tid == 0)
    out[0] = ((red[0] + red[1]) + (red[2] + red[3])) * (1.0f / (float)(BQ * YQ));
}

extern "C" void kernel_launch(void* const* d_in, const int* in_sizes, int n_in,
                              void* d_out, int out_size, void* d_ws, size_t ws_size,
                              hipStream_t stream) {
  const float* x      = (const float*)d_in[0];
  const float* target = (const float*)d_in[1];
  const int*   c2t    = (const int*)d_in[2];
  const float* embed  = (const float*)d_in[3];
  const float* cw     = (const float*)d_in[4];
  const float* cb     = (const float*)d_in[5];
  const float* fw     = (const float*)d_in[6];
  const float* fb     = (const float*)d_in[7];

  char* ws = (char*)d_ws;
  ushort* xb = (ushort*)(ws);                   //  8,388,608 B
  ushort* xT = (ushort*)(ws + 8388608);         //  8,388,608 B
  ushort* Wp = (ushort*)(ws + 16777216);        //  1,179,648 B
  ushort* U  = (ushort*)(ws + 17956864);        //  9,175,040 B (YPAD x D bf16)
  float* part = (float*)(ws + 27131904);        //  35,688 B (per-label loss)
  // optional bf16 alpha copy: 146,227,200 B
  const size_t ABF_OFF = 27262976;
  const size_t ABF_END = ABF_OFF + (size_t)BQ * YQ * SQ * 2;
  bool use_abf = (ws_size >= ABF_END);
  ushort* abf = use_abf ? (ushort*)(ws + ABF_OFF) : (ushort*)0;

  float* out       = (float*)d_out;
  float* out_y     = out;                               // [B][Y]
  float* out_loss  = out + (size_t)BQ * YQ;             // scalar
  float* out_alpha = out + (size_t)BQ * YQ + 1;         // [B][Y][S]
  float* out_m     = out_alpha + (size_t)BQ * YQ * SQ;  // [B][Y][D]

  hipMemsetAsync(U, 0, (size_t)YPAD * DQ * 2, stream);

  k_prep_x<<<dim3(SQ / 32, DQ / 32, BQ), dim3(32, 32), 0, stream>>>(x, xb, xT);
  k_pack_w<<<dim3((KQ * DQ * EP + 255) / 256), 256, 0, stream>>>(cw, Wp);
  k_conv<<<dim3(4, (YQ + 3) / 4), 256, 0, stream>>>(c2t, embed, Wp, cb, U);
  k_scores<<<dim3(SQ / 128, (YQ + 127) / 128, BQ), 256, 0, stream>>>(U, xb, out_alpha);
  k_softmax<<<dim3(BQ * YQ), 256, 0, stream>>>(out_alpha, abf);
  if (use_abf)
    k_pv<true><<<dim3(DQ / 128, (YQ + 127) / 128, BQ), 256, 0, stream>>>(out_alpha, abf, xT, out_m);
  else
    k_pv<false><<<dim3(DQ / 128, (YQ + 127) / 128, BQ), 256, 0, stream>>>(out_alpha, abf, xT, out_m);
  k_final<<<dim3(YQ), 256, 0, stream>>>(out_m, fw, fb, target, out_y, part);
  k_loss_fin<<<1, 256, 0, stream>>>(part, out_loss);
}